// Round 8
// baseline (137.658 us; speedup 1.0000x reference)
//
#include <hip/hip_runtime.h>
#include <hip/hip_bf16.h>

#define B_   64
#define L_   2048
#define DTS  8
#define DSEQ 120
#define H_   64
#define TILE 64
#define NT   32          // max tiles per batch row

typedef unsigned short u16;
typedef unsigned int   u32;
typedef __bf16 bf16x8 __attribute__((ext_vector_type(8)));
typedef short  short8 __attribute__((ext_vector_type(8)));
typedef float  f32x4  __attribute__((ext_vector_type(4)));

__device__ __forceinline__ float rrelu_f(float x) {   // slope = (1/8+1/3)/2 = 11/48
    return x >= 0.f ? x : x * 0.22916666666666666f;
}
__device__ __forceinline__ u16 f2bf(float x) {        // f32 -> bf16 bits, RNE
    unsigned u = __float_as_uint(x);
    return (u16)((u + 0x7FFFu + ((u >> 16) & 1u)) >> 16);
}
__device__ __forceinline__ float bf2f(u16 u) {
    return __uint_as_float(((unsigned)u) << 16);
}

// ---------- kernel 1: setup (W hi/lo pack in B-frag order + parallel qlast) ----------
__global__ void setup_kernel(const float* __restrict__ ts, const float* __restrict__ seq,
                             const int* __restrict__ lengths,
                             const float* __restrict__ Wk, const float* __restrict__ Wv,
                             const float* __restrict__ Wq, const float* __restrict__ bq,
                             u16* __restrict__ pkh, u16* __restrict__ pkl,
                             u16* __restrict__ pvh, u16* __restrict__ pvl,
                             float* __restrict__ qlast)
{
    const int blk = blockIdx.x, tid = threadIdx.x;
    if (blk < 64) {
        // packed[((ni*4+kk)*64 + lane)*8 + j] = W[(kk*32 + (lane>>4)*8 + j)*64 + (ni*16 + (lane&15))]
        const int f = blk * 256 + tid;
        const int idx = f & 8191;
        const bool isK = f < 8192;
        const float* W = isK ? Wk : Wv;
        u16* hi = isK ? pkh : pvh;
        u16* lo = isK ? pkl : pvl;
        const int j = idx & 7, lane = (idx >> 3) & 63, kk = (idx >> 9) & 3, ni = idx >> 11;
        const int kd = kk * 32 + (lane >> 4) * 8 + j;
        const int n  = ni * 16 + (lane & 15);
        const float v = W[kd * H_ + n];
        const u16 h = f2bf(v);
        hi[idx] = h;
        lo[idx] = f2bf(v - bf2f(h));
    } else {
        // qlast for b = blk-64, split over 4 waves (32 d-values each), LDS reduce
        const int b = blk - 64;
        const int h = tid & 63, part = tid >> 6;       // wave-uniform part
        const int l = lengths[b] - 1;
        const float* tsr = ts  + ((size_t)b * L_ + l) * DTS;
        const float* sqr = seq + ((size_t)b * L_ + l) * DSEQ;
        float acc = 0.f;
        if (part == 0) {
            #pragma unroll
            for (int d = 0; d < DTS; ++d)  acc += tsr[d] * Wq[d * H_ + h];
            #pragma unroll
            for (int d = DTS; d < 32; ++d) acc += sqr[d - DTS] * Wq[d * H_ + h];
        } else {
            const int d0 = part * 32;
            #pragma unroll
            for (int i = 0; i < 32; ++i)
                acc += sqr[d0 + i - DTS] * Wq[(d0 + i) * H_ + h];
        }
        __shared__ float qred[4][H_];
        qred[part][h] = acc;
        __syncthreads();
        if (tid < H_)
            qlast[b * H_ + tid] = rrelu_f(qred[0][tid] + qred[1][tid] +
                                          qred[2][tid] + qred[3][tid] + bq[tid]);
    }
}

// ---------- kernel 2: one 512-thread block per (b, tile); LDS-FREE A loads ----------
// A-frag A[m=l16][k=quad*8+j] = 8 CONTIGUOUS f32 per lane, 16B-aligned (ts row=32B,
// seq row=480B) -> load straight from global, convert in-register to hi/lo bf16.
// A wave's 64 lanes cover 16 complete rows -> full cache-line utilization.
// No x staging, ~1.3 KB LDS -> occupancy capped only by threads (4 blk/CU = 32 waves/CU).
// Waves 0-3: K-side (48 MFMAs + scores + exp). Waves 4-7: V-side (48 MFMAs + p.V).
__global__ __launch_bounds__(512) void tile_kernel(
    const float* __restrict__ ts, const float* __restrict__ seq,
    const int* __restrict__ lengths,
    const u16* __restrict__ pkh, const u16* __restrict__ pkl,
    const u16* __restrict__ pvh, const u16* __restrict__ pvl,
    const float* __restrict__ bk, const float* __restrict__ bv,
    const float* __restrict__ qlast,
    float* __restrict__ pden, float* __restrict__ pnum)
{
    const int b = blockIdx.y, t = blockIdx.x;
    const int len = lengths[b];
    const int ls = t * TILE;
    if (ls >= len) return;                    // block-uniform early exit
    const int nv = min(TILE, len - ls);
    const int pb = b * NT + t;

    const int tid = threadIdx.x, wave = tid >> 6, lane = tid & 63;
    const int quad = lane >> 4, l16 = lane & 15;
    const int mg = wave & 3, isV = wave >> 2;
    const int m0 = mg * 16;

    __shared__ float scp[TILE];               // p (post-exp) per row
    __shared__ float red[4][H_];
    __shared__ float wd[4];

    // ---- direct global A loads: this lane's row, 4 kk-frags x 32B ----
    const int row = ls + m0 + l16;            // global l; row <= 2047 always
    const float* tsr = ts  + ((size_t)b * L_ + row) * DTS;
    const float* sqr = seq + ((size_t)b * L_ + row) * DSEQ;
    f32x4 a0[4], a1[4];
    #pragma unroll
    for (int kk = 0; kk < 4; ++kk) {
        const int k0 = kk * 32 + quad * 8;    // feature base; 8-run never straddles ts/seq
        const float* src = (k0 < DTS) ? (tsr + k0) : (sqr + (k0 - DTS));
        a0[kk] = *(const f32x4*)src;          // independent dwordx4 loads,
        a1[kk] = *(const f32x4*)(src + 4);    // one waitcnt covers all 8
    }
    // ---- in-register split to hi/lo bf16 ----
    bf16x8 ah[4], al[4];
    #pragma unroll
    for (int kk = 0; kk < 4; ++kk) {
        short8 h8, l8;
        #pragma unroll
        for (int j = 0; j < 4; ++j) {
            const u16 h0 = f2bf(a0[kk][j]);
            h8[j] = (short)h0; l8[j] = (short)f2bf(a0[kk][j] - bf2f(h0));
            const u16 h1 = f2bf(a1[kk][j]);
            h8[4 + j] = (short)h1; l8[4 + j] = (short)f2bf(a1[kk][j] - bf2f(h1));
        }
        ah[kk] = __builtin_bit_cast(bf16x8, h8);
        al[kk] = __builtin_bit_cast(bf16x8, l8);
    }

    // ---- wave-specialized B source: K waves -> Wk pack, V waves -> Wv pack ----
    const u16* bhp = isV ? pvh : pkh;
    const u16* blp = isV ? pvl : pkl;
    const float* bias = isV ? bv : bk;
    float bb[4];
    #pragma unroll
    for (int ni = 0; ni < 4; ++ni) bb[ni] = bias[ni * 16 + l16];

    // ---- 48 MFMAs: split-bf16 (hi*hi + lo*hi + hi*lo) ----
    float cd[4][4];   // rrelu(result) per n-group per r
    #pragma unroll
    for (int ni = 0; ni < 4; ++ni) {
        f32x4 acc = {0.f, 0.f, 0.f, 0.f};
        #pragma unroll
        for (int kk = 0; kk < 4; ++kk) {
            const size_t off = (size_t)((ni * 4 + kk) * 64 + lane) * 8;
            const bf16x8 bh = *(const bf16x8*)(bhp + off);   // coalesced 16B, L1/L2-hot
            const bf16x8 bl = *(const bf16x8*)(blp + off);
            acc = __builtin_amdgcn_mfma_f32_16x16x32_bf16(ah[kk], bh, acc, 0, 0, 0);
            acc = __builtin_amdgcn_mfma_f32_16x16x32_bf16(al[kk], bh, acc, 0, 0, 0);
            acc = __builtin_amdgcn_mfma_f32_16x16x32_bf16(ah[kk], bl, acc, 0, 0, 0);
        }
        // C/D map: col = ni*16 + l16, row = m0 + quad*4 + r
        #pragma unroll
        for (int r = 0; r < 4; ++r) cd[ni][r] = rrelu_f(acc[r] + bb[ni]);
    }

    if (!isV) {
        // ---- K path: scores for rows m0+quad*4+r, reduce over 16 h-lanes, exp ----
        float qv[4];
        #pragma unroll
        for (int ni = 0; ni < 4; ++ni) qv[ni] = qlast[b * H_ + ni * 16 + l16];
        float ps[4] = {0.f, 0.f, 0.f, 0.f};
        #pragma unroll
        for (int ni = 0; ni < 4; ++ni)
            #pragma unroll
            for (int r = 0; r < 4; ++r) ps[r] += qv[ni] * cd[ni][r];
        #pragma unroll
        for (int mk = 1; mk < 16; mk <<= 1)
            #pragma unroll
            for (int r = 0; r < 4; ++r) ps[r] += __shfl_xor(ps[r], mk);
        // max-free softmax: |s| <= ~13 for these distributions; clamp defensively
        float p4[4], ds = 0.f;
        #pragma unroll
        for (int r = 0; r < 4; ++r) {
            const int rr = m0 + quad * 4 + r;
            p4[r] = (rr < nv) ? __expf(fminf(ps[r], 80.f)) : 0.f;
            ds += p4[r];
        }
        if (l16 == 0) {
            #pragma unroll
            for (int r = 0; r < 4; ++r) scp[m0 + quad * 4 + r] = p4[r];
        }
        ds += __shfl_xor(ds, 16);
        ds += __shfl_xor(ds, 32);
        if (lane == 0) wd[mg] = ds;
    }
    __syncthreads();

    if (isV) {
        // ---- V path: p.V over this wave's 16 rows ----
        float pr[4];
        #pragma unroll
        for (int r = 0; r < 4; ++r) pr[r] = scp[m0 + quad * 4 + r];   // broadcast
        float pv[4];
        #pragma unroll
        for (int ni = 0; ni < 4; ++ni) {
            float a = 0.f;
            #pragma unroll
            for (int r = 0; r < 4; ++r) a += pr[r] * cd[ni][r];
            pv[ni] = a;
        }
        #pragma unroll
        for (int mk = 16; mk < 64; mk <<= 1)
            #pragma unroll
            for (int ni = 0; ni < 4; ++ni) pv[ni] += __shfl_xor(pv[ni], mk);
        if (quad == 0) {
            #pragma unroll
            for (int ni = 0; ni < 4; ++ni) red[mg][ni * 16 + l16] = pv[ni];
        }
    }
    __syncthreads();

    // ---- plain stores of per-tile partials (no atomics anywhere) ----
    if (tid < H_)
        pnum[(size_t)pb * H_ + tid] = red[0][tid] + red[1][tid] + red[2][tid] + red[3][tid];
    if (tid == 0)
        pden[pb] = wd[0] + wd[1] + wd[2] + wd[3];
}

// ---------- kernel 3: plain-sum combine ----------
__global__ void combine_kernel(const int* __restrict__ lengths,
                               const float* __restrict__ pden,
                               const float* __restrict__ pnum,
                               float* __restrict__ out)
{
    const int b = blockIdx.x, h = threadIdx.x;   // 64 blocks x 64 threads
    const int nt = (lengths[b] + TILE - 1) / TILE;
    float den = 0.f, num = 0.f;
    #pragma unroll 8
    for (int t = 0; t < nt; ++t) {
        den += pden[b * NT + t];
        num += pnum[(size_t)(b * NT + t) * H_ + h];
    }
    out[b * H_ + h] = num / den;
}

extern "C" void kernel_launch(void* const* d_in, const int* in_sizes, int n_in,
                              void* d_out, int out_size, void* d_ws, size_t ws_size,
                              hipStream_t stream)
{
    const float* ts      = (const float*)d_in[0];
    const float* seq     = (const float*)d_in[1];
    const int*   lengths = (const int*)d_in[2];
    const float* Wk      = (const float*)d_in[3];
    const float* bk      = (const float*)d_in[4];
    const float* Wq      = (const float*)d_in[5];
    const float* bq      = (const float*)d_in[6];
    const float* Wv      = (const float*)d_in[7];
    const float* bv      = (const float*)d_in[8];

    float* ws    = (float*)d_ws;
    float* qlast = ws;                         // 4096 f32
    float* pden  = ws + 4096;                  // 2048
    float* pnum  = ws + 6144;                  // 64*32*64 = 131072
    u16*   packw = (u16*)(ws + 137216);        // 4 x 8192 u16 = 64 KB
    u16* pkh = packw;
    u16* pkl = packw + 8192;
    u16* pvh = packw + 16384;
    u16* pvl = packw + 24576;

    setup_kernel<<<dim3(128), dim3(256), 0, stream>>>(ts, seq, lengths, Wk, Wv, Wq, bq,
                                                      pkh, pkl, pvh, pvl, qlast);
    tile_kernel<<<dim3(NT, B_), dim3(512), 0, stream>>>(ts, seq, lengths,
                                                        pkh, pkl, pvh, pvl, bk, bv,
                                                        qlast, pden, pnum);
    combine_kernel<<<dim3(B_), dim3(H_), 0, stream>>>(lengths, pden, pnum, (float*)d_out);
}

// Round 9
// 132.587 us; speedup vs baseline: 1.0382x; 1.0382x over previous
//
#include <hip/hip_runtime.h>
#include <hip/hip_bf16.h>

#define B_   64
#define L_   2048
#define DTS  8
#define DSEQ 120
#define H_   64
#define TILE 128
#define NT   16          // max tiles per batch row (2048/128)

typedef unsigned short u16;
typedef unsigned int   u32;
typedef __bf16 bf16x8 __attribute__((ext_vector_type(8)));
typedef short  short8 __attribute__((ext_vector_type(8)));
typedef float  f32x4  __attribute__((ext_vector_type(4)));

__device__ __forceinline__ float rrelu_f(float x) {   // slope = (1/8+1/3)/2 = 11/48
    return x >= 0.f ? x : x * 0.22916666666666666f;
}
__device__ __forceinline__ u16 f2bf(float x) {        // f32 -> bf16 bits, RNE
    unsigned u = __float_as_uint(x);
    return (u16)((u + 0x7FFFu + ((u >> 16) & 1u)) >> 16);
}
__device__ __forceinline__ float bf2f(u16 u) {
    return __uint_as_float(((unsigned)u) << 16);
}

// ---------- kernel 1: setup (W hi/lo pack in B-frag order + parallel qlast) ----------
__global__ void setup_kernel(const float* __restrict__ ts, const float* __restrict__ seq,
                             const int* __restrict__ lengths,
                             const float* __restrict__ Wk, const float* __restrict__ Wv,
                             const float* __restrict__ Wq, const float* __restrict__ bq,
                             u16* __restrict__ pkh, u16* __restrict__ pkl,
                             u16* __restrict__ pvh, u16* __restrict__ pvl,
                             float* __restrict__ qlast)
{
    const int blk = blockIdx.x, tid = threadIdx.x;
    if (blk < 64) {
        // packed[((ni*4+kk)*64 + lane)*8 + j] = W[(kk*32 + (lane>>4)*8 + j)*64 + (ni*16 + (lane&15))]
        const int f = blk * 256 + tid;
        const int idx = f & 8191;
        const bool isK = f < 8192;
        const float* W = isK ? Wk : Wv;
        u16* hi = isK ? pkh : pvh;
        u16* lo = isK ? pkl : pvl;
        const int j = idx & 7, lane = (idx >> 3) & 63, kk = (idx >> 9) & 3, ni = idx >> 11;
        const int kd = kk * 32 + (lane >> 4) * 8 + j;
        const int n  = ni * 16 + (lane & 15);
        const float v = W[kd * H_ + n];
        const u16 h = f2bf(v);
        hi[idx] = h;
        lo[idx] = f2bf(v - bf2f(h));
    } else {
        // qlast for b = blk-64, split over 4 waves (32 d-values each), LDS reduce
        const int b = blk - 64;
        const int h = tid & 63, part = tid >> 6;
        const int l = lengths[b] - 1;
        const float* tsr = ts  + ((size_t)b * L_ + l) * DTS;
        const float* sqr = seq + ((size_t)b * L_ + l) * DSEQ;
        float acc = 0.f;
        if (part == 0) {
            #pragma unroll
            for (int d = 0; d < DTS; ++d)  acc += tsr[d] * Wq[d * H_ + h];
            #pragma unroll
            for (int d = DTS; d < 32; ++d) acc += sqr[d - DTS] * Wq[d * H_ + h];
        } else {
            const int d0 = part * 32;
            #pragma unroll
            for (int i = 0; i < 32; ++i)
                acc += sqr[d0 + i - DTS] * Wq[(d0 + i) * H_ + h];
        }
        __shared__ float qred[4][H_];
        qred[part][h] = acc;
        __syncthreads();
        if (tid < H_)
            qlast[b * H_ + tid] = rrelu_f(qred[0][tid] + qred[1][tid] +
                                          qred[2][tid] + qred[3][tid] + bq[tid]);
    }
}

// ---------- kernel 2: 512-thread block per (b, 128-row tile) ----------
// Each wave handles TWO 16-row m-groups (g=0: rows 16*w4.., g=1: rows 64+16*w4..).
// B-fragments load once per ni and feed both m-groups -> B L1 traffic halved vs
// one-mg-per-wave. All 16 A-loads issue as one batch (forces a large VGPR live
// set -> real memory-level parallelism; R8's VGPR=40 serialized them).
// Waves 0-3 = K side (scores+exp), waves 4-7 = V side (p.V). No atomics.
__global__ __launch_bounds__(512) void tile_kernel(
    const float* __restrict__ ts, const float* __restrict__ seq,
    const int* __restrict__ lengths,
    const u16* __restrict__ pkh, const u16* __restrict__ pkl,
    const u16* __restrict__ pvh, const u16* __restrict__ pvl,
    const float* __restrict__ bk, const float* __restrict__ bv,
    const float* __restrict__ qlast,
    float* __restrict__ pden, float* __restrict__ pnum)
{
    const int b = blockIdx.y, t = blockIdx.x;
    const int len = lengths[b];
    const int ls = t * TILE;
    if (ls >= len) return;                    // block-uniform early exit
    const int nv = min(TILE, len - ls);
    const int pb = b * NT + t;

    const int tid = threadIdx.x, wave = tid >> 6, lane = tid & 63;
    const int quad = lane >> 4, l16 = lane & 15;
    const int w4 = wave & 3, isV = wave >> 2;

    __shared__ float scp[TILE];               // p (post-exp) per row
    __shared__ float red[4][H_];
    __shared__ float wd[4];

    // ---- batched direct-global A loads for BOTH m-groups (16 dwordx4) ----
    f32x4 a0[2][4], a1[2][4];
    #pragma unroll
    for (int g = 0; g < 2; ++g) {
        const int row = ls + (w4 + 4 * g) * 16 + l16;       // < 2048 always
        const float* tsr = ts  + ((size_t)b * L_ + row) * DTS;
        const float* sqr = seq + ((size_t)b * L_ + row) * DSEQ;
        #pragma unroll
        for (int kk = 0; kk < 4; ++kk) {
            const int k0 = kk * 32 + quad * 8;              // 8-run never straddles ts/seq
            const float* src = (k0 < DTS) ? (tsr + k0) : (sqr + (k0 - DTS));
            a0[g][kk] = *(const f32x4*)src;
            a1[g][kk] = *(const f32x4*)(src + 4);
        }
    }
    // ---- in-register split to hi/lo bf16 ----
    bf16x8 ah[2][4], al[2][4];
    #pragma unroll
    for (int g = 0; g < 2; ++g)
        #pragma unroll
        for (int kk = 0; kk < 4; ++kk) {
            short8 h8, l8;
            #pragma unroll
            for (int j = 0; j < 4; ++j) {
                const u16 h0 = f2bf(a0[g][kk][j]);
                h8[j] = (short)h0; l8[j] = (short)f2bf(a0[g][kk][j] - bf2f(h0));
                const u16 h1 = f2bf(a1[g][kk][j]);
                h8[4 + j] = (short)h1; l8[4 + j] = (short)f2bf(a1[g][kk][j] - bf2f(h1));
            }
            ah[g][kk] = __builtin_bit_cast(bf16x8, h8);
            al[g][kk] = __builtin_bit_cast(bf16x8, l8);
        }

    // ---- wave-specialized B source ----
    const u16* bhp = isV ? pvh : pkh;
    const u16* blp = isV ? pvl : pkl;
    const float* bias = isV ? bv : bk;

    // ---- per-ni: load B frags ONCE, use for both m-groups (96 MFMAs total) ----
    float cd[2][4][4];
    #pragma unroll
    for (int ni = 0; ni < 4; ++ni) {
        bf16x8 bh[4], bl[4];
        #pragma unroll
        for (int kk = 0; kk < 4; ++kk) {
            const size_t off = (size_t)((ni * 4 + kk) * 64 + lane) * 8;
            bh[kk] = *(const bf16x8*)(bhp + off);
            bl[kk] = *(const bf16x8*)(blp + off);
        }
        const float bb = bias[ni * 16 + l16];
        #pragma unroll
        for (int g = 0; g < 2; ++g) {
            f32x4 acc = {0.f, 0.f, 0.f, 0.f};
            #pragma unroll
            for (int kk = 0; kk < 4; ++kk) {
                acc = __builtin_amdgcn_mfma_f32_16x16x32_bf16(ah[g][kk], bh[kk], acc, 0, 0, 0);
                acc = __builtin_amdgcn_mfma_f32_16x16x32_bf16(al[g][kk], bh[kk], acc, 0, 0, 0);
                acc = __builtin_amdgcn_mfma_f32_16x16x32_bf16(ah[g][kk], bl[kk], acc, 0, 0, 0);
            }
            // C/D map: col = ni*16 + l16, row(in-mg) = quad*4 + r
            #pragma unroll
            for (int r = 0; r < 4; ++r) cd[g][ni][r] = rrelu_f(acc[r] + bb);
        }
    }

    if (!isV) {
        // ---- K path: scores, reduce over 16 h-lanes, max-free exp ----
        float qv[4];
        #pragma unroll
        for (int ni = 0; ni < 4; ++ni) qv[ni] = qlast[b * H_ + ni * 16 + l16];
        float ps[2][4] = {{0.f,0.f,0.f,0.f},{0.f,0.f,0.f,0.f}};
        #pragma unroll
        for (int g = 0; g < 2; ++g)
            #pragma unroll
            for (int ni = 0; ni < 4; ++ni)
                #pragma unroll
                for (int r = 0; r < 4; ++r) ps[g][r] += qv[ni] * cd[g][ni][r];
        #pragma unroll
        for (int mk = 1; mk < 16; mk <<= 1)
            #pragma unroll
            for (int g = 0; g < 2; ++g)
                #pragma unroll
                for (int r = 0; r < 4; ++r) ps[g][r] += __shfl_xor(ps[g][r], mk);
        float ds = 0.f;
        #pragma unroll
        for (int g = 0; g < 2; ++g) {
            float p4[4];
            #pragma unroll
            for (int r = 0; r < 4; ++r) {
                const int rr = (w4 + 4 * g) * 16 + quad * 4 + r;
                p4[r] = (rr < nv) ? __expf(fminf(ps[g][r], 80.f)) : 0.f;
                ds += p4[r];
            }
            if (l16 == 0) {
                #pragma unroll
                for (int r = 0; r < 4; ++r)
                    scp[(w4 + 4 * g) * 16 + quad * 4 + r] = p4[r];
            }
        }
        ds += __shfl_xor(ds, 16);
        ds += __shfl_xor(ds, 32);
        if (lane == 0) wd[w4] = ds;          // 32-row partial denominator
    }
    __syncthreads();

    if (isV) {
        // ---- V path: p.V over this wave's 32 rows ----
        float pr[2][4];
        #pragma unroll
        for (int g = 0; g < 2; ++g)
            #pragma unroll
            for (int r = 0; r < 4; ++r)
                pr[g][r] = scp[(w4 + 4 * g) * 16 + quad * 4 + r];   // broadcast
        float pv[4];
        #pragma unroll
        for (int ni = 0; ni < 4; ++ni) {
            float a = 0.f;
            #pragma unroll
            for (int g = 0; g < 2; ++g)
                #pragma unroll
                for (int r = 0; r < 4; ++r) a += pr[g][r] * cd[g][ni][r];
            pv[ni] = a;
        }
        #pragma unroll
        for (int mk = 16; mk < 64; mk <<= 1)
            #pragma unroll
            for (int ni = 0; ni < 4; ++ni) pv[ni] += __shfl_xor(pv[ni], mk);
        if (quad == 0) {
            #pragma unroll
            for (int ni = 0; ni < 4; ++ni) red[w4][ni * 16 + l16] = pv[ni];
        }
    }
    __syncthreads();

    // ---- plain stores of per-tile partials ----
    if (tid < H_)
        pnum[(size_t)pb * H_ + tid] = red[0][tid] + red[1][tid] + red[2][tid] + red[3][tid];
    if (tid == 0)
        pden[pb] = wd[0] + wd[1] + wd[2] + wd[3];
}

// ---------- kernel 3: plain-sum combine ----------
__global__ void combine_kernel(const int* __restrict__ lengths,
                               const float* __restrict__ pden,
                               const float* __restrict__ pnum,
                               float* __restrict__ out)
{
    const int b = blockIdx.x, h = threadIdx.x;   // 64 blocks x 64 threads
    const int nt = (lengths[b] + TILE - 1) / TILE;
    float den = 0.f, num = 0.f;
    #pragma unroll 4
    for (int t = 0; t < nt; ++t) {
        den += pden[b * NT + t];
        num += pnum[(size_t)(b * NT + t) * H_ + h];
    }
    out[b * H_ + h] = num / den;
}

extern "C" void kernel_launch(void* const* d_in, const int* in_sizes, int n_in,
                              void* d_out, int out_size, void* d_ws, size_t ws_size,
                              hipStream_t stream)
{
    const float* ts      = (const float*)d_in[0];
    const float* seq     = (const float*)d_in[1];
    const int*   lengths = (const int*)d_in[2];
    const float* Wk      = (const float*)d_in[3];
    const float* bk      = (const float*)d_in[4];
    const float* Wq      = (const float*)d_in[5];
    const float* bq      = (const float*)d_in[6];
    const float* Wv      = (const float*)d_in[7];
    const float* bv      = (const float*)d_in[8];

    float* ws    = (float*)d_ws;
    float* qlast = ws;                         // 4096 f32
    float* pden  = ws + 4096;                  // 64*16 = 1024
    float* pnum  = ws + 5120;                  // 64*16*64 = 65536
    u16*   packw = (u16*)(ws + 70656);         // 4 x 8192 u16 = 64 KB
    u16* pkh = packw;
    u16* pkl = packw + 8192;
    u16* pvh = packw + 16384;
    u16* pvl = packw + 24576;

    setup_kernel<<<dim3(128), dim3(256), 0, stream>>>(ts, seq, lengths, Wk, Wv, Wq, bq,
                                                      pkh, pkl, pvh, pvl, qlast);
    tile_kernel<<<dim3(NT, B_), dim3(512), 0, stream>>>(ts, seq, lengths,
                                                        pkh, pkl, pvh, pvl, bk, bv,
                                                        qlast, pden, pnum);
    combine_kernel<<<dim3(B_), dim3(H_), 0, stream>>>(lengths, pden, pnum, (float*)d_out);
}